// Round 1
// baseline (386.638 us; speedup 1.0000x reference)
//
#include <hip/hip_runtime.h>
#include <math.h>

#define Nn 32
#define Cc 64
#define Tt 128
#define Vv 25
#define Kk 204800   // C*T*V
#define Hh 256
#define Ee 4
#define KC 400
#define NBLK_A 512  // Kk / KC

__device__ __forceinline__ float elu1(float v) { return v > 0.0f ? v : expm1f(v); }

// ---------------- Kernel A: split-K  h0_partial[b][n][h] = sum_{k in chunk b} x[n,k]*W0[k,h]
__global__ __launch_bounds__(256) void kA(const float* __restrict__ x,
                                          const float* __restrict__ W0,
                                          float* __restrict__ partials) {
  __shared__ float xs[Nn][KC];   // 51.2 KB
  const int tid = threadIdx.x;
  const int b = blockIdx.x;
  const int k0 = b * KC;

  // stage x[0:32, k0:k0+KC): row-contiguous float4 loads, contiguous LDS writes
  for (int j = tid; j < Nn * (KC / 4); j += 256) {
    int n = j / (KC / 4);
    int col = j - n * (KC / 4);
    float4 v = *(const float4*)(x + (size_t)n * Kk + k0 + col * 4);
    *(float4*)&xs[n][col * 4] = v;
  }
  __syncthreads();

  const int hq = tid & 63;   // h-quad: h = hq*4 .. hq*4+3
  const int p  = tid >> 6;   // n-part: n = p*8 .. p*8+7
  const int n0 = p * 8;
  const float* W0p = W0 + (size_t)k0 * Hh + hq * 4;

  float acc[8][4];
  #pragma unroll
  for (int i = 0; i < 8; ++i)
    #pragma unroll
    for (int c = 0; c < 4; ++c) acc[i][c] = 0.0f;

  for (int kk = 0; kk < KC; kk += 4) {
    // 8 broadcast ds_read_b128 (same-address across wave -> conflict-free)
    float xv[8][4];
    #pragma unroll
    for (int i = 0; i < 8; ++i)
      *(float4*)xv[i] = *(const float4*)&xs[n0 + i][kk];
    #pragma unroll
    for (int u = 0; u < 4; ++u) {
      float4 w4 = *(const float4*)(W0p + (size_t)(kk + u) * Hh);  // coalesced 1KB/wave
      #pragma unroll
      for (int i = 0; i < 8; ++i) {
        acc[i][0] = fmaf(xv[i][u], w4.x, acc[i][0]);
        acc[i][1] = fmaf(xv[i][u], w4.y, acc[i][1]);
        acc[i][2] = fmaf(xv[i][u], w4.z, acc[i][2]);
        acc[i][3] = fmaf(xv[i][u], w4.w, acc[i][3]);
      }
    }
  }
  #pragma unroll
  for (int i = 0; i < 8; ++i) {
    float4 o = make_float4(acc[i][0], acc[i][1], acc[i][2], acc[i][3]);
    *(float4*)&partials[((size_t)(b * Nn + n0 + i) << 8) + hq * 4] = o;
  }
}

// ---------------- Kernel B1: reduce 512 partials, + b0, ELU  -> hb[n][h]
__global__ __launch_bounds__(256) void kB1(const float* __restrict__ partials,
                                           const float* __restrict__ b0,
                                           float* __restrict__ hb) {
  const int n  = blockIdx.x >> 3;
  const int hc = blockIdx.x & 7;
  const int tid = threadIdx.x;
  const int hl = tid & 31;
  const int bsub = tid >> 5;
  const int h = hc * 32 + hl;
  float s = 0.0f;
  for (int j = 0; j < 64; ++j) {
    int b = bsub * 64 + j;
    s += partials[((size_t)(b * Nn + n) << 8) + h];
  }
  __shared__ float red[8][32];
  red[bsub][hl] = s;
  __syncthreads();
  if (tid < 32) {
    float tot = 0.0f;
    #pragma unroll
    for (int sI = 0; sI < 8; ++sI) tot += red[sI][tid];
    int hh = hc * 32 + tid;
    hb[n * Hh + hh] = elu1(tot + b0[hh]);
  }
}

// ---------------- Kernel B2: h2 = elu(hb@W1+b1); logits = h2@W2+b2; softmax -> wgt[n][e]
__global__ __launch_bounds__(256) void kB2(const float* __restrict__ hb,
                                           const float* __restrict__ W1,
                                           const float* __restrict__ b1,
                                           const float* __restrict__ W2,
                                           const float* __restrict__ b2,
                                           float* __restrict__ wgt) {
  const int n = blockIdx.x;
  const int tid = threadIdx.x;
  __shared__ float hbs[Hh];
  hbs[tid] = hb[n * Hh + tid];
  __syncthreads();
  float s = b1[tid];
  for (int j = 0; j < Hh; ++j) s = fmaf(hbs[j], W1[j * Hh + tid], s);
  float h2 = elu1(s);
  float le[Ee];
  #pragma unroll
  for (int e = 0; e < Ee; ++e) le[e] = h2 * W2[tid * Ee + e];
  __shared__ float red[Ee][4];
  const int lane = tid & 63;
  const int wid  = tid >> 6;
  #pragma unroll
  for (int e = 0; e < Ee; ++e) {
    float v = le[e];
    for (int off = 32; off > 0; off >>= 1) v += __shfl_down(v, off, 64);
    if (lane == 0) red[e][wid] = v;
  }
  __syncthreads();
  if (tid == 0) {
    float lg[Ee];
    float m = -1e30f;
    #pragma unroll
    for (int e = 0; e < Ee; ++e) {
      lg[e] = red[e][0] + red[e][1] + red[e][2] + red[e][3] + b2[e];
      m = fmaxf(m, lg[e]);
    }
    float den = 0.0f;
    #pragma unroll
    for (int e = 0; e < Ee; ++e) { lg[e] = expf(lg[e] - m); den += lg[e]; }
    float inv = 1.0f / den;
    #pragma unroll
    for (int e = 0; e < Ee; ++e) wgt[n * Ee + e] = lg[e] * inv;
  }
}

// ---------------- Kernel C: per (n,t): AS[v][w] = sum_e wgt[n][e]*A[e][t][v][w];
//                  out[n][c][t][w] = sum_v x[n][c][t][v] * AS[v][w]
__global__ __launch_bounds__(256) void kC(const float* __restrict__ x,
                                          const float* __restrict__ A,
                                          const float* __restrict__ wgt,
                                          float* __restrict__ out) {
  const int b = blockIdx.x;
  const int n = b >> 7;        // /128
  const int t = b & 127;
  __shared__ float AS[Vv * Vv];    // 625
  __shared__ float xsl[Cc * Vv];   // 1600
  float wv[Ee];
  #pragma unroll
  for (int e = 0; e < Ee; ++e) wv[e] = wgt[n * Ee + e];

  for (int idx = threadIdx.x; idx < Vv * Vv; idx += 256) {
    float s = 0.0f;
    #pragma unroll
    for (int e = 0; e < Ee; ++e)
      s = fmaf(wv[e], A[(size_t)(e * Tt + t) * (Vv * Vv) + idx], s);
    AS[idx] = s;
  }
  const float* xb = x + (size_t)n * (Cc * Tt * Vv) + (size_t)t * Vv;
  for (int idx = threadIdx.x; idx < Cc * Vv; idx += 256) {
    int c = idx / Vv;
    int v = idx - c * Vv;
    xsl[idx] = xb[(size_t)c * (Tt * Vv) + v];
  }
  __syncthreads();
  float* ob = out + (size_t)n * (Cc * Tt * Vv) + (size_t)t * Vv;
  for (int idx = threadIdx.x; idx < Cc * Vv; idx += 256) {
    int c = idx / Vv;
    int w = idx - c * Vv;
    float s = 0.0f;
    #pragma unroll
    for (int v = 0; v < Vv; ++v)
      s = fmaf(xsl[c * Vv + v], AS[v * Vv + w], s);
    ob[(size_t)c * (Tt * Vv) + w] = s;
  }
}

extern "C" void kernel_launch(void* const* d_in, const int* in_sizes, int n_in,
                              void* d_out, int out_size, void* d_ws, size_t ws_size,
                              hipStream_t stream) {
  const float* x  = (const float*)d_in[0];
  const float* W0 = (const float*)d_in[1];
  const float* b0 = (const float*)d_in[2];
  const float* W1 = (const float*)d_in[3];
  const float* b1 = (const float*)d_in[4];
  const float* W2 = (const float*)d_in[5];
  const float* b2 = (const float*)d_in[6];
  const float* A  = (const float*)d_in[7];
  float* out = (float*)d_out;

  float* partials = (float*)d_ws;                          // 512*32*256 floats = 16.78 MB
  float* hb  = partials + (size_t)NBLK_A * Nn * Hh;        // 8192 floats
  float* wgt = hb + Nn * Hh;                               // 128 floats

  kA <<<NBLK_A, 256, 0, stream>>>(x, W0, partials);
  kB1<<<256,    256, 0, stream>>>(partials, b0, hb);
  kB2<<<Nn,     256, 0, stream>>>(hb, W1, b1, W2, b2, wgt);
  kC <<<Nn * Tt,256, 0, stream>>>(x, A, wgt, out);
}